// Round 3
// baseline (228.413 us; speedup 1.0000x reference)
//
#include <hip/hip_runtime.h>

// y[..., 2k]   = T[k][0][0]*x[2k] + T[k][0][1]*x[2k+1]
// y[..., 2k+1] = T[k][1][0]*x[2k] + T[k][1][1]*x[2k+1]
//
// Structure: twiddle depends only on the position within the 4096-wide row,
// and is reused by all 8192 rows. Each thread owns one float4-column p,
// loads its two twiddle float4s ONCE into registers, then streams R rows of
// x->y. x/y accesses stay perfectly coalesced (consecutive lanes =
// consecutive columns); x and y are touched exactly once -> nontemporal.

typedef float f4 __attribute__((ext_vector_type(4)));  // native vec for nontemporal builtins

#define ROW4 1024            // 4096 floats / 4 per row
#define ROWS_PER_BLOCK 16

__global__ __launch_bounds__(256) void butterfly_kernel(
    const f4* __restrict__ x,
    const f4* __restrict__ tw,   // tw[k] = {t00,t01,t10,t11} for pair k
    f4* __restrict__ y)
{
    const int p  = blockIdx.x * 256 + threadIdx.x;   // float4 column [0,1024)
    const int r0 = blockIdx.y * ROWS_PER_BLOCK;

    // Twiddle for this column: pairs 2p and 2p+1. Loaded once per thread.
    const f4 t0 = tw[2 * p];
    const f4 t1 = tw[2 * p + 1];

    const f4* xp = x + (size_t)r0 * ROW4 + p;
    f4*       yp = y + (size_t)r0 * ROW4 + p;

#pragma unroll 4
    for (int r = 0; r < ROWS_PER_BLOCK; ++r) {
        f4 xv = __builtin_nontemporal_load(xp + (size_t)r * ROW4);
        f4 yv;
        yv.x = t0.x * xv.x + t0.y * xv.y;
        yv.y = t0.z * xv.x + t0.w * xv.y;
        yv.z = t1.x * xv.z + t1.y * xv.w;
        yv.w = t1.z * xv.z + t1.w * xv.w;
        __builtin_nontemporal_store(yv, yp + (size_t)r * ROW4);
    }
}

extern "C" void kernel_launch(void* const* d_in, const int* in_sizes, int n_in,
                              void* d_out, int out_size, void* d_ws, size_t ws_size,
                              hipStream_t stream) {
    const f4* x  = (const f4*)d_in[0];   // (4, 2048, 4096) fp32
    const f4* tw = (const f4*)d_in[1];   // (2048, 2, 2) fp32
    f4* y = (f4*)d_out;

    const int n_rows = out_size / 4096;          // 8192

    dim3 block(256);
    dim3 grid(ROW4 / 256, n_rows / ROWS_PER_BLOCK);  // (4, 512) = 2048 blocks
    butterfly_kernel<<<grid, block, 0, stream>>>(x, tw, y);
}

// Round 4
// 220.498 us; speedup vs baseline: 1.0359x; 1.0359x over previous
//
#include <hip/hip_runtime.h>

// y[..., 2k]   = T[k][0][0]*x[2k] + T[k][0][1]*x[2k+1]
// y[..., 2k+1] = T[k][1][0]*x[2k] + T[k][1][1]*x[2k+1]
//
// Each thread owns one float4-column p, loads its two twiddle float4s once
// into registers, streams ROWS_PER_BLOCK rows x->y. Fully unrolled so all
// loads issue up front (max memory-level parallelism); 4096 blocks = 16/CU
// for wave-level latency hiding. x/y touched exactly once -> nontemporal.

typedef float f4 __attribute__((ext_vector_type(4)));

#define ROW4 1024            // 4096 floats / 4 per row
#define ROWS_PER_BLOCK 8

__global__ __launch_bounds__(256) void butterfly_kernel(
    const f4* __restrict__ x,
    const f4* __restrict__ tw,   // tw[k] = {t00,t01,t10,t11} for pair k
    f4* __restrict__ y)
{
    const int p  = blockIdx.x * 256 + threadIdx.x;   // float4 column [0,1024)
    const int r0 = blockIdx.y * ROWS_PER_BLOCK;

    const f4 t0 = tw[2 * p];
    const f4 t1 = tw[2 * p + 1];

    const f4* xp = x + (size_t)r0 * ROW4 + p;
    f4*       yp = y + (size_t)r0 * ROW4 + p;

    f4 xv[ROWS_PER_BLOCK];
#pragma unroll
    for (int r = 0; r < ROWS_PER_BLOCK; ++r)
        xv[r] = __builtin_nontemporal_load(xp + (size_t)r * ROW4);

#pragma unroll
    for (int r = 0; r < ROWS_PER_BLOCK; ++r) {
        f4 yv;
        yv.x = t0.x * xv[r].x + t0.y * xv[r].y;
        yv.y = t0.z * xv[r].x + t0.w * xv[r].y;
        yv.z = t1.x * xv[r].z + t1.y * xv[r].w;
        yv.w = t1.z * xv[r].z + t1.w * xv[r].w;
        __builtin_nontemporal_store(yv, yp + (size_t)r * ROW4);
    }
}

extern "C" void kernel_launch(void* const* d_in, const int* in_sizes, int n_in,
                              void* d_out, int out_size, void* d_ws, size_t ws_size,
                              hipStream_t stream) {
    const f4* x  = (const f4*)d_in[0];   // (4, 2048, 4096) fp32
    const f4* tw = (const f4*)d_in[1];   // (2048, 2, 2) fp32
    f4* y = (f4*)d_out;

    const int n_rows = out_size / 4096;  // 8192

    dim3 block(256);
    dim3 grid(ROW4 / 256, n_rows / ROWS_PER_BLOCK);  // (4, 1024) = 4096 blocks
    butterfly_kernel<<<grid, block, 0, stream>>>(x, tw, y);
}